// Round 2
// baseline (650.523 us; speedup 1.0000x reference)
//
#include <hip/hip_runtime.h>

// Problem constants
#define N4 4096
#define FF 32
#define KK 6
#define OO 128
#define BB 4

typedef __attribute__((ext_vector_type(8))) short  short8;   // 8 bf16 (4 VGPRs) MFMA A/B frag
typedef __attribute__((ext_vector_type(4))) float  f32x4;    // MFMA C/D frag
typedef __attribute__((ext_vector_type(4))) int    i32x4;    // 16B copy
typedef __attribute__((ext_vector_type(2))) unsigned int u32x2;

__device__ __forceinline__ float b2f(unsigned short h) {
    union { float f; unsigned u; } v; v.u = ((unsigned)h) << 16; return v.f;
}
__device__ __forceinline__ unsigned short f2b(float f) {
    union { float f; unsigned u; } v; v.f = f;
    unsigned r = (v.u + 0x7FFFu + ((v.u >> 16) & 1u)) >> 16;
    return (unsigned short)r;
}

// ---------------------------------------------------------------------------
// Wc[k][f][o] = bf16(theta[k] * W[k][f][o]);  K*F*O = 24576 elems
__global__ __launch_bounds__(256) void make_wc(const float* __restrict__ W,
                                               const float* __restrict__ theta,
                                               unsigned short* __restrict__ Wc) {
    int idx = blockIdx.x * 256 + threadIdx.x;
    int k = idx >> 12;                 // F*O = 4096
    Wc[idx] = f2b(theta[k] * W[idx]);
}

// ---------------------------------------------------------------------------
// x [B][N][F] f32  ->  T0 [B][F][N] bf16 (transposed).  grid B*(N/64)=256
__global__ __launch_bounds__(256) void x_to_t(const float* __restrict__ x,
                                              unsigned short* __restrict__ T0) {
    __shared__ __align__(16) unsigned short Ol[32][72];
    int tid = threadIdx.x, bid = blockIdx.x;
    int b = bid >> 6; long n0 = (long)(bid & 63) * 64;
    int nl = tid >> 2, fg = (tid & 3) * 8;
    const float* src = x + ((long)b * N4 + n0 + nl) * FF + fg;
    f32x4 v0 = *(const f32x4*)src;
    f32x4 v1 = *(const f32x4*)(src + 4);
#pragma unroll
    for (int e = 0; e < 4; ++e) {
        Ol[fg + e][nl]     = f2b(v0[e]);
        Ol[fg + 4 + e][nl] = f2b(v1[e]);
    }
    __syncthreads();
    int f = tid >> 3, col = (tid & 7) * 8;
    *(i32x4*)(T0 + ((long)b * FF + f) * N4 + n0 + col) = *(const i32x4*)&Ol[f][col];
}

// ---------------------------------------------------------------------------
// L f32 -> Lb bf16, elementwise streaming.  64Mi elems, 8/thread, grid 32768.
__global__ __launch_bounds__(256) void transcode(const float* __restrict__ L,
                                                 unsigned short* __restrict__ Lb) {
    long g = (long)blockIdx.x * 256 + threadIdx.x;
    long base = g * 8;
    f32x4 v0 = *(const f32x4*)(L + base);
    f32x4 v1 = *(const f32x4*)(L + base + 4);
    i32x4 pk;
    pk[0] = (unsigned)f2b(v0[0]) | ((unsigned)f2b(v0[1]) << 16);
    pk[1] = (unsigned)f2b(v0[2]) | ((unsigned)f2b(v0[3]) << 16);
    pk[2] = (unsigned)f2b(v1[0]) | ((unsigned)f2b(v1[1]) << 16);
    pk[3] = (unsigned)f2b(v1[2]) | ((unsigned)f2b(v1[3]) << 16);
    *(i32x4*)(Lb + base) = pk;
}

// ---------------------------------------------------------------------------
// Barrier-free streaming GEMM.  Each WAVE owns one (b, 16-row m-strip, k-chunk):
//   P[s][b][m0..m0+16][0..32] = L_b[strip, k0..k0+1024] @ T^T
// grid 1024 blocks x 256 thr (4 independent waves/block), no LDS, no barriers.
// A frag: lane l16 -> row m0+l16, k = ks*32 + quad*8 .. +8  (16B/lane)
// B frag: lane l16 -> f (= l16 / l16+16), same k                (16B/lane, L2-hot)
template <bool AF32>
__global__ __launch_bounds__(256) void gemm_stream(const unsigned short* __restrict__ Ab,
                                                   const float* __restrict__ Af,
                                                   const unsigned short* __restrict__ Tt, // [B][F][N]
                                                   float* __restrict__ P) {               // [4][B][N][F]
    int tid = threadIdx.x, bid = blockIdx.x;
    int s = bid & 3, b = (bid >> 2) & 3, sg = bid >> 4;
    int wave = tid >> 6, lane = tid & 63, quad = lane >> 4, l16 = lane & 15;
    long m0 = (long)(sg * 4 + wave) * 16;
    long k0 = (long)s * 1024;

    const unsigned short* Ap = AF32 ? nullptr
        : Ab + ((long)b * N4 + m0 + l16) * N4 + k0 + quad * 8;
    const float* Fp = AF32
        ? Af + ((long)b * N4 + m0 + l16) * N4 + k0 + quad * 8 : nullptr;
    const unsigned short* B0p = Tt + ((long)b * FF + l16) * N4 + k0 + quad * 8;
    const unsigned short* B1p = B0p + (long)16 * N4;

    f32x4 acc0 = {0.f,0.f,0.f,0.f}, acc1 = {0.f,0.f,0.f,0.f};

    auto ldA = [&](int ks) -> short8 {
        if (AF32) {
            f32x4 v0 = *(const f32x4*)(Fp + ks * 32);
            f32x4 v1 = *(const f32x4*)(Fp + ks * 32 + 4);
            short8 r;
#pragma unroll
            for (int e = 0; e < 4; ++e) {
                r[e]     = (short)f2b(v0[e]);
                r[4 + e] = (short)f2b(v1[e]);
            }
            return r;
        }
        return *(const short8*)(Ap + ks * 32);
    };
    auto ldB = [&](const unsigned short* p, int ks) -> short8 {
        return *(const short8*)(p + ks * 32);
    };

    short8 Ar[4], B0r[4], B1r[4];
#pragma unroll
    for (int i = 0; i < 4; ++i) {
        Ar[i] = ldA(i); B0r[i] = ldB(B0p, i); B1r[i] = ldB(B1p, i);
    }
#pragma unroll 4
    for (int ks = 0; ks < 32; ++ks) {
        int sl = ks & 3;
        short8 a = Ar[sl], b0 = B0r[sl], b1 = B1r[sl];
        if (ks + 4 < 32) {
            Ar[sl]  = ldA(ks + 4);
            B0r[sl] = ldB(B0p, ks + 4);
            B1r[sl] = ldB(B1p, ks + 4);
        }
        acc0 = __builtin_amdgcn_mfma_f32_16x16x32_bf16(a, b0, acc0, 0, 0, 0);
        acc1 = __builtin_amdgcn_mfma_f32_16x16x32_bf16(a, b1, acc1, 0, 0, 0);
    }

    // D frag: row = quad*4 + r (within strip), col = l16
    float* Pp = P + (((long)s * BB + b) * N4 + m0) * FF;
#pragma unroll
    for (int r = 0; r < 4; ++r) {
        int row = quad * 4 + r;
        Pp[(long)row * FF + l16]      = acc0[r];
        Pp[(long)row * FF + 16 + l16] = acc1[r];
    }
}

// ---------------------------------------------------------------------------
// T_k = a * (sum_s P[s]) + c * T_{k-2};  writes bf16 transposed [B][F][N]
__global__ __launch_bounds__(256) void reduce_pass(const float* __restrict__ P,
                                                   const unsigned short* __restrict__ Tpp,
                                                   unsigned short* __restrict__ Tout,
                                                   float a, float c) {
    __shared__ __align__(16) unsigned short Tpl[32][72];
    __shared__ __align__(16) unsigned short Ol[32][72];
    int tid = threadIdx.x, bid = blockIdx.x;
    int b = bid >> 6; long n0 = (long)(bid & 63) * 64;
    if (Tpp) {
        int f = tid >> 3, col = (tid & 7) * 8;
        *(i32x4*)&Tpl[f][col] = *(const i32x4*)(Tpp + ((long)b * FF + f) * N4 + n0 + col);
    }
    __syncthreads();
    int nl = tid >> 2, fg = (tid & 3) * 8;
    const float* p0 = P + ((long)b * N4 + n0 + nl) * FF + fg;
    float sum[8];
#pragma unroll
    for (int e = 0; e < 8; ++e) sum[e] = 0.f;
#pragma unroll
    for (int s = 0; s < 4; ++s) {
        const float* ps = p0 + (long)s * BB * N4 * FF;
        f32x4 v0 = *(const f32x4*)ps;
        f32x4 v1 = *(const f32x4*)(ps + 4);
#pragma unroll
        for (int e = 0; e < 4; ++e) { sum[e] += v0[e]; sum[4 + e] += v1[e]; }
    }
#pragma unroll
    for (int e = 0; e < 8; ++e) {
        float val = a * sum[e];
        if (Tpp) val += c * b2f(Tpl[fg + e][nl]);
        Ol[fg + e][nl] = f2b(val);
    }
    __syncthreads();
    int f = tid >> 3, col = (tid & 7) * 8;
    *(i32x4*)(Tout + ((long)b * FF + f) * N4 + n0 + col) = *(const i32x4*)&Ol[f][col];
}

// ---------------------------------------------------------------------------
// out[b][n][o] = sum_k sum_f T_k[b][f][n] * Wc[k][f][o]   (Wc already has theta)
__global__ __launch_bounds__(256) void proj(const unsigned short* __restrict__ T, // [K][B][F][N]
                                            const unsigned short* __restrict__ Wc, // [K*F][O]
                                            float* __restrict__ out) {
    __shared__ __align__(16) unsigned short Tl[192][72];
    __shared__ __align__(16) unsigned short Wl[192][64];
    int tid = threadIdx.x, bid = blockIdx.x;
    int b = bid >> 7; int rem = bid & 127;
    long n0 = (long)(rem >> 1) * 64; int oh = rem & 1;
#pragma unroll
    for (int it = 0; it < 6; ++it) {
        int row = it * 32 + (tid >> 3);    // kf index
        int col = (tid & 7) * 8;
        int k = row >> 5, f = row & 31;
        *(i32x4*)&Tl[row][col] =
            *(const i32x4*)(T + (((long)k * BB + b) * FF + f) * N4 + n0 + col);
        *(i32x4*)&Wl[row][col] = *(const i32x4*)(Wc + (long)row * OO + oh * 64 + col);
    }
    __syncthreads();
    int ol = tid & 63;
    int nb = (tid >> 6) * 16;
    float acc[16];
#pragma unroll
    for (int r = 0; r < 16; ++r) acc[r] = 0.f;
    for (int kf = 0; kf < 192; ++kf) {
        float w = b2f(Wl[kf][ol]);
#pragma unroll
        for (int rv = 0; rv < 2; ++rv) {
            short8 tv = *(const short8*)&Tl[kf][nb + rv * 8];
#pragma unroll
            for (int e = 0; e < 8; ++e)
                acc[rv * 8 + e] += b2f((unsigned short)tv[e]) * w;
        }
    }
    int o = oh * 64 + ol;
#pragma unroll
    for (int r = 0; r < 16; ++r)
        out[((long)b * N4 + n0 + nb + r) * OO + o] = acc[r];
}

// ---------------------------------------------------------------------------
extern "C" void kernel_launch(void* const* d_in, const int* in_sizes, int n_in,
                              void* d_out, int out_size, void* d_ws, size_t ws_size,
                              hipStream_t stream) {
    const float* x     = (const float*)d_in[0];
    const float* L     = (const float*)d_in[1];
    const float* W     = (const float*)d_in[2];
    const float* theta = (const float*)d_in[3];
    float* out = (float*)d_out;
    char* ws = (char*)d_ws;

    const size_t LB_BYTES = (size_t)BB * N4 * N4 * 2;          // 134,217,728
    const size_t T_SLOT   = (size_t)BB * FF * N4;              // elems per slot
    const size_t T_BYTES  = (size_t)KK * T_SLOT * 2;           // 6,291,456
    const size_t P_BYTES  = (size_t)4 * BB * N4 * FF * 4;      // 8,388,608
    const size_t WC_BYTES = (size_t)KK * FF * OO * 2;          // 49,152

    bool haveL = ws_size >= LB_BYTES + T_BYTES + P_BYTES + WC_BYTES;
    size_t off = haveL ? LB_BYTES : 0;
    unsigned short* Lb = (unsigned short*)ws;
    unsigned short* T  = (unsigned short*)(ws + off);
    float*          P  = (float*)(ws + off + T_BYTES);
    unsigned short* Wc = (unsigned short*)(ws + off + T_BYTES + P_BYTES);

    make_wc<<<96, 256, 0, stream>>>(W, theta, Wc);
    x_to_t<<<256, 256, 0, stream>>>(x, T);   // slot 0 = bf16(x)^T

    if (haveL)
        transcode<<<32768, 256, 0, stream>>>(L, Lb);

    // pass 1: T1 = L @ T0
    if (haveL)
        gemm_stream<false><<<1024, 256, 0, stream>>>(Lb, nullptr, T, P);
    else
        gemm_stream<true><<<1024, 256, 0, stream>>>(nullptr, L, T, P);
    reduce_pass<<<256, 256, 0, stream>>>(P, nullptr, T + 1 * T_SLOT, 1.f, 0.f);

    // passes 2..5: T_k = 2 L @ T_{k-1} - T_{k-2}
    for (int k = 2; k < KK; ++k) {
        if (haveL)
            gemm_stream<false><<<1024, 256, 0, stream>>>(Lb, nullptr, T + (k - 1) * T_SLOT, P);
        else
            gemm_stream<true><<<1024, 256, 0, stream>>>(nullptr, L, T + (k - 1) * T_SLOT, P);
        reduce_pass<<<256, 256, 0, stream>>>(P, T + (k - 2) * T_SLOT, T + k * T_SLOT, 2.f, -1.f);
    }

    proj<<<512, 256, 0, stream>>>(T, Wc, out);
}

// Round 3
// 535.098 us; speedup vs baseline: 1.2157x; 1.2157x over previous
//
#include <hip/hip_runtime.h>

// Problem constants
#define N4 4096
#define FF 32
#define KK 6
#define OO 128
#define BB 4

typedef __attribute__((ext_vector_type(8))) short  short8;   // 8 bf16 MFMA A/B frag
typedef __attribute__((ext_vector_type(4))) float  f32x4;
typedef __attribute__((ext_vector_type(4))) int    i32x4;
typedef __attribute__((ext_vector_type(2))) unsigned int u32x2;

__device__ __forceinline__ float b2f(unsigned short h) {
    union { float f; unsigned u; } v; v.u = ((unsigned)h) << 16; return v.f;
}
__device__ __forceinline__ unsigned short f2b(float f) {
    union { float f; unsigned u; } v; v.f = f;
    unsigned r = (v.u + 0x7FFFu + ((v.u >> 16) & 1u)) >> 16;
    return (unsigned short)r;
}

// Tb frag layout: element (f, n) of T lives at
//   tb_idx(b, ks=n>>5, half=f>>4, lane=((n>>3)&3)*16 + (f&15)) + (n&7)
__device__ __forceinline__ long tb_idx(int b, int ks, int half, int lane) {
    return ((((long)b * 128 + ks) * 2 + half) * 64 + lane) * 8;
}

// ---------------------------------------------------------------------------
// Wc[k][f][o] = bf16(theta[k] * W[k][f][o])
__global__ __launch_bounds__(256) void make_wc(const float* __restrict__ W,
                                               const float* __restrict__ theta,
                                               unsigned short* __restrict__ Wc) {
    int idx = blockIdx.x * 256 + threadIdx.x;
    int k = idx >> 12;
    Wc[idx] = f2b(theta[k] * W[idx]);
}

// ---------------------------------------------------------------------------
// x [B][N][F] f32 -> T0 in Tb frag layout.  grid B*64=256 blocks (b, nc).
__global__ __launch_bounds__(256) void x_to_t(const float* __restrict__ x,
                                              unsigned short* __restrict__ T0) {
    __shared__ __align__(16) unsigned short Ol[32][72];   // [f][n-local]
    int tid = threadIdx.x, bid = blockIdx.x;
    int b = bid >> 6; int nc = bid & 63; long n0 = (long)nc * 64;
    int nl = tid >> 2, fg = (tid & 3) * 8;
    const float* src = x + ((long)b * N4 + n0 + nl) * FF + fg;
    f32x4 v0 = *(const f32x4*)src;
    f32x4 v1 = *(const f32x4*)(src + 4);
#pragma unroll
    for (int e = 0; e < 4; ++e) {
        Ol[fg + e][nl]     = f2b(v0[e]);
        Ol[fg + 4 + e][nl] = f2b(v1[e]);
    }
    __syncthreads();
    int ks_l = tid >> 7, half = (tid >> 6) & 1, lane = tid & 63;
    int quad = lane >> 4, l16 = lane & 15;
    int f = half * 16 + l16, nloc = ks_l * 32 + quad * 8;
    *(i32x4*)(T0 + tb_idx(b, nc * 2 + ks_l, half, lane)) = *(const i32x4*)&Ol[f][nloc];
}

// ---------------------------------------------------------------------------
// Pass 1 fused: reads f32 L (coalesced 256B/row chunks), wave-local LDS permute
// to frag layout, writes Lb (wave-contiguous 1KB) AND computes T1 = L @ T0.
// grid 1024 blocks (b, ms) x 4 waves (s = split-k quarter). No __syncthreads.
__global__ __launch_bounds__(256) void gemm_pass1(const float* __restrict__ L,
                                                  unsigned short* __restrict__ Lb,
                                                  const unsigned short* __restrict__ Tb0,
                                                  float* __restrict__ P) {
    __shared__ __align__(16) unsigned short Sw[4][2][2][64][8];  // [wave][buf][ks_loc][lane][e]
    int tid = threadIdx.x, bid = blockIdx.x;
    int b = bid >> 8, ms = bid & 255;
    int w = tid >> 6, lane = tid & 63, l16 = lane & 15;
    int rgrp = lane >> 4;                       // row group for reads
    // read: instr j covers rows j*4+rgrp, k chunk l16*4 (256B contiguous/row)
    const float* Ls = L + ((long)b * N4 + ms * 16 + rgrp) * N4 + (long)w * 1024 + l16 * 4;
    int ks_loc_w = l16 >> 3, quad_w = (l16 >> 1) & 3, e0 = (l16 & 1) * 4;
    const unsigned short* Bbase = Tb0 + tb_idx(b, w * 32, 0, lane);
    unsigned short* LbBase = Lb + (((long)(b * 256 + ms) * 128 + w * 32) * 64 + lane) * 8;

    f32x4 acc0 = {0.f,0.f,0.f,0.f}, acc1 = {0.f,0.f,0.f,0.f};
    f32x4 v[4], vn[4];
#pragma unroll
    for (int j = 0; j < 4; ++j) v[j] = *(const f32x4*)(Ls + (long)j * 4 * N4);

    for (int it = 0; it < 16; ++it) {
        if (it + 1 < 16) {
#pragma unroll
            for (int j = 0; j < 4; ++j)
                vn[j] = *(const f32x4*)(Ls + (long)j * 4 * N4 + (it + 1) * 64);
        }
        // B frags for the two ks of this iteration (L2-hot, wave-contiguous)
        short8 b00 = *(const short8*)(Bbase + (long)(it * 2 + 0) * 1024);
        short8 b01 = *(const short8*)(Bbase + (long)(it * 2 + 0) * 1024 + 512);
        short8 b10 = *(const short8*)(Bbase + (long)(it * 2 + 1) * 1024);
        short8 b11 = *(const short8*)(Bbase + (long)(it * 2 + 1) * 1024 + 512);
        // convert + LDS permute (wave-local, double-buffered)
        unsigned short* Sb = &Sw[w][it & 1][0][0][0];
#pragma unroll
        for (int j = 0; j < 4; ++j) {
            u32x2 pk;
            pk[0] = (unsigned)f2b(v[j][0]) | ((unsigned)f2b(v[j][1]) << 16);
            pk[1] = (unsigned)f2b(v[j][2]) | ((unsigned)f2b(v[j][3]) << 16);
            int lane_o = quad_w * 16 + j * 4 + rgrp;
            *(u32x2*)(Sb + (ks_loc_w * 64 + lane_o) * 8 + e0) = pk;
        }
#pragma unroll
        for (int h = 0; h < 2; ++h) {
            short8 af = *(const short8*)(Sb + (h * 64 + lane) * 8);
            *(short8*)(LbBase + (long)(it * 2 + h) * 512) = af;  // 1KB wave-contiguous
            acc0 = __builtin_amdgcn_mfma_f32_16x16x32_bf16(af, h ? b10 : b00, acc0, 0, 0, 0);
            acc1 = __builtin_amdgcn_mfma_f32_16x16x32_bf16(af, h ? b11 : b01, acc1, 0, 0, 0);
        }
#pragma unroll
        for (int j = 0; j < 4; ++j) v[j] = vn[j];
    }
    // P frag-major: [s][b][ms][half][lane][4]
    *(f32x4*)(P + ((((long)(w * 4 + b) * 256 + ms) * 2 + 0) * 64 + lane) * 4) = acc0;
    *(f32x4*)(P + ((((long)(w * 4 + b) * 256 + ms) * 2 + 1) * 64 + lane) * 4) = acc1;
}

// ---------------------------------------------------------------------------
// Passes 2..5: all-frag-layout streaming GEMM, fully contiguous loads.
// grid 1024 blocks (b, ms) x 4 waves (s).  No LDS, no barriers.
__global__ __launch_bounds__(256) void gemm_frag(const unsigned short* __restrict__ Lb,
                                                 const unsigned short* __restrict__ Tb,
                                                 float* __restrict__ P) {
    int tid = threadIdx.x, bid = blockIdx.x;
    int b = bid >> 8, ms = bid & 255;
    int s = tid >> 6, lane = tid & 63;
    const unsigned short* Ap = Lb + (((long)(b * 256 + ms) * 128 + s * 32) * 64 + lane) * 8;
    const unsigned short* Bp = Tb + tb_idx(b, s * 32, 0, lane);

    f32x4 acc0 = {0.f,0.f,0.f,0.f}, acc1 = {0.f,0.f,0.f,0.f};
    short8 Ar[4], B0r[4], B1r[4];
#pragma unroll
    for (int i = 0; i < 4; ++i) {
        Ar[i]  = *(const short8*)(Ap + (long)i * 512);
        B0r[i] = *(const short8*)(Bp + (long)i * 1024);
        B1r[i] = *(const short8*)(Bp + (long)i * 1024 + 512);
    }
#pragma unroll 4
    for (int ks = 0; ks < 32; ++ks) {
        int sl = ks & 3;
        short8 a = Ar[sl], b0 = B0r[sl], b1 = B1r[sl];
        if (ks + 4 < 32) {
            Ar[sl]  = *(const short8*)(Ap + (long)(ks + 4) * 512);
            B0r[sl] = *(const short8*)(Bp + (long)(ks + 4) * 1024);
            B1r[sl] = *(const short8*)(Bp + (long)(ks + 4) * 1024 + 512);
        }
        acc0 = __builtin_amdgcn_mfma_f32_16x16x32_bf16(a, b0, acc0, 0, 0, 0);
        acc1 = __builtin_amdgcn_mfma_f32_16x16x32_bf16(a, b1, acc1, 0, 0, 0);
    }
    *(f32x4*)(P + ((((long)(s * 4 + b) * 256 + ms) * 2 + 0) * 64 + lane) * 4) = acc0;
    *(f32x4*)(P + ((((long)(s * 4 + b) * 256 + ms) * 2 + 1) * 64 + lane) * 4) = acc1;
}

// ---------------------------------------------------------------------------
// T_k = a * (sum_s P[s]) + c * T_{k-2};  D-frag -> LDS -> Tb frag layout.
// grid B*64=256 blocks (b, nc covering 64 n = 4 mstrips).
__global__ __launch_bounds__(256) void reduce_frag(const float* __restrict__ P,
                                                   const unsigned short* __restrict__ Tpp,
                                                   unsigned short* __restrict__ Tout,
                                                   float a, float c) {
    __shared__ float Sl[32][66];      // [f][n-local]
    int tid = threadIdx.x, bid = blockIdx.x;
    int b = bid >> 6, nc = bid & 63;
#pragma unroll
    for (int i = 0; i < 2; ++i) {
        int fid = i * 256 + tid;                  // (ms_l, h, lane)
        int ms_l = fid >> 7, h = (fid >> 6) & 1, lane = fid & 63;
        int quad = lane >> 4, l16 = lane & 15;
        long base = ((((long)b * 256 + nc * 4 + ms_l) * 2 + h) * 64 + lane) * 4;
        f32x4 sum = *(const f32x4*)(P + base);
#pragma unroll
        for (int s = 1; s < 4; ++s) {
            f32x4 v = *(const f32x4*)(P + base + (long)s * 524288);
#pragma unroll
            for (int e = 0; e < 4; ++e) sum[e] += v[e];
        }
        int f = h * 16 + l16, nl = ms_l * 16 + quad * 4;
#pragma unroll
        for (int r = 0; r < 4; ++r) Sl[f][nl + r] = sum[r];
    }
    __syncthreads();
    int ks_l = tid >> 7, half = (tid >> 6) & 1, lane = tid & 63;
    int quad = lane >> 4, l16 = lane & 15;
    int f = half * 16 + l16, nl = ks_l * 32 + quad * 8;
    long oidx = tb_idx(b, nc * 2 + ks_l, half, lane);
    const unsigned short* tp = Tpp ? (Tpp + oidx) : nullptr;
    i32x4 pk;
#pragma unroll
    for (int p = 0; p < 4; ++p) {
        float v0 = a * Sl[f][nl + p * 2];
        float v1 = a * Sl[f][nl + p * 2 + 1];
        if (tp) { v0 += c * b2f(tp[p * 2]); v1 += c * b2f(tp[p * 2 + 1]); }
        pk[p] = (unsigned)f2b(v0) | ((unsigned)f2b(v1) << 16);
    }
    *(i32x4*)(Tout + oidx) = pk;
}

// ---------------------------------------------------------------------------
// out[b][n][o] = sum_k sum_f T_k[b](f,n) * Wc[k][f][o]
// grid = B * 64 * 2(o-halves) = 512 blocks.
__global__ __launch_bounds__(256) void proj(const unsigned short* __restrict__ T, // K slots, Tb layout
                                            const unsigned short* __restrict__ Wc,
                                            float* __restrict__ out) {
    __shared__ __align__(16) unsigned short Tl[192][72];
    __shared__ __align__(16) unsigned short Wl[192][64];
    int tid = threadIdx.x, bid = blockIdx.x;
    int b = bid >> 7; int rem = bid & 127;
    int nc = rem >> 1; long n0 = (long)nc * 64; int oh = rem & 1;
    const long T_SLOT = (long)BB * FF * N4;
#pragma unroll
    for (int it = 0; it < 6; ++it) {
        int row = it * 32 + (tid >> 3);    // kf index
        int col = (tid & 7) * 8;           // n-local
        int k = row >> 5, f = row & 31;
        int ks = nc * 2 + (col >> 5), half = f >> 4;
        int lane = ((col & 31) >> 3) * 16 + (f & 15);
        *(i32x4*)&Tl[row][col] = *(const i32x4*)(T + (long)k * T_SLOT + tb_idx(b, ks, half, lane));
        *(i32x4*)&Wl[row][col] = *(const i32x4*)(Wc + (long)row * OO + oh * 64 + col);
    }
    __syncthreads();
    int ol = tid & 63;
    int nb = (tid >> 6) * 16;
    float acc[16];
#pragma unroll
    for (int r = 0; r < 16; ++r) acc[r] = 0.f;
    for (int kf = 0; kf < 192; ++kf) {
        float w = b2f(Wl[kf][ol]);
#pragma unroll
        for (int rv = 0; rv < 2; ++rv) {
            short8 tv = *(const short8*)&Tl[kf][nb + rv * 8];
#pragma unroll
            for (int e = 0; e < 8; ++e)
                acc[rv * 8 + e] += b2f((unsigned short)tv[e]) * w;
        }
    }
    int o = oh * 64 + ol;
#pragma unroll
    for (int r = 0; r < 16; ++r)
        out[((long)b * N4 + n0 + nb + r) * OO + o] = acc[r];
}

// ---------------------------------------------------------------------------
extern "C" void kernel_launch(void* const* d_in, const int* in_sizes, int n_in,
                              void* d_out, int out_size, void* d_ws, size_t ws_size,
                              hipStream_t stream) {
    const float* x     = (const float*)d_in[0];
    const float* L     = (const float*)d_in[1];
    const float* W     = (const float*)d_in[2];
    const float* theta = (const float*)d_in[3];
    float* out = (float*)d_out;
    char* ws = (char*)d_ws;

    const size_t LB_BYTES = (size_t)BB * N4 * N4 * 2;     // 128 MiB
    const size_t T_SLOT   = (size_t)BB * FF * N4;         // elems per slot
    const size_t T_BYTES  = (size_t)KK * T_SLOT * 2;      // 6 MiB
    const size_t P_BYTES  = (size_t)4 * BB * N4 * FF * 4; // 8 MiB

    unsigned short* Lb = (unsigned short*)ws;
    unsigned short* T  = (unsigned short*)(ws + LB_BYTES);
    float*          P  = (float*)(ws + LB_BYTES + T_BYTES);
    unsigned short* Wc = (unsigned short*)(ws + LB_BYTES + T_BYTES + P_BYTES);

    make_wc<<<96, 256, 0, stream>>>(W, theta, Wc);
    x_to_t<<<256, 256, 0, stream>>>(x, T);          // slot 0 = frag-layout bf16(x^T)

    // pass 1: T1 = L @ T0, fused f32->frag transcode of L
    gemm_pass1<<<1024, 256, 0, stream>>>(L, Lb, T, P);
    reduce_frag<<<256, 256, 0, stream>>>(P, nullptr, T + 1 * T_SLOT, 1.f, 0.f);

    // passes 2..5: T_k = 2 L @ T_{k-1} - T_{k-2}
    for (int k = 2; k < KK; ++k) {
        gemm_frag<<<1024, 256, 0, stream>>>(Lb, T + (k - 1) * T_SLOT, P);
        reduce_frag<<<256, 256, 0, stream>>>(P, T + (k - 2) * T_SLOT, T + k * T_SLOT, 2.f, -1.f);
    }

    proj<<<512, 256, 0, stream>>>(T, Wc, out);
}